// Round 4
// baseline (525.167 us; speedup 1.0000x reference)
//
#include <hip/hip_runtime.h>
#include <cstddef>

#define BB 8
#define SS 1024
#define DD 768
#define HH 8
#define DKK 96
#define FFF 1024
#define MM (BB*SS)
#define QVW 1536                       // merged Q|KV row width
#define SM_SCALE 0.10206207261596577f  // 1/sqrt(96)
#define NTILES 16
#define NPAIR  136                     // 16*17/2 packed causal tiles

typedef unsigned short ushort_t;
typedef short short8 __attribute__((ext_vector_type(8)));
typedef float f32x4 __attribute__((ext_vector_type(4)));
typedef ushort_t us4 __attribute__((ext_vector_type(4)));

__device__ __forceinline__ ushort_t f2b(float f) {
    union { float f; unsigned u; } x; x.f = f;
    unsigned r = x.u + 0x7fffu + ((x.u >> 16) & 1u);   // RNE
    return (ushort_t)(r >> 16);
}
__device__ __forceinline__ float b2f(ushort_t u) {
    union { unsigned u; float f; } x; x.u = ((unsigned)u) << 16;
    return x.f;
}
// async global->LDS, 16B per lane; LDS dest = wave-uniform base + lane*16
__device__ __forceinline__ void gload16(const ushort_t* g, void* lds_base) {
    __builtin_amdgcn_global_load_lds(
        (const __attribute__((address_space(1))) unsigned int*)g,
        (__attribute__((address_space(3))) unsigned int*)lds_base, 16, 0, 0);
}

// ---------------------------------------------------------------------------
__global__ __launch_bounds__(256) void zerof(float* __restrict__ p, int n)
{
    const int i = blockIdx.x * 256 + threadIdx.x;
    if (i < n) p[i] = 0.f;
}

// Weight cast+transpose: W (KxN fp32) -> Wt (NxK bf16). grid (N/32, K/32).
__global__ __launch_bounds__(256) void castWT(
    const float* __restrict__ W, ushort_t* __restrict__ Wt, int K, int N)
{
    __shared__ float T[32][33];
    const int tx = threadIdx.x & 31, ty = threadIdx.x >> 5;
    const int n0 = blockIdx.x * 32, k0 = blockIdx.y * 32;
    #pragma unroll
    for (int r = 0; r < 4; ++r)
        T[ty + 8*r][tx] = W[(size_t)(k0 + ty + 8*r) * N + n0 + tx];
    __syncthreads();
    #pragma unroll
    for (int r = 0; r < 4; ++r)
        Wt[(size_t)(n0 + ty + 8*r) * K + k0 + tx] = f2b(T[tx][ty + 8*r]);
}

__global__ __launch_bounds__(256) void cast_f2b(
    const float* __restrict__ in, ushort_t* __restrict__ out, int n4)
{
    const int i = blockIdx.x * 256 + threadIdx.x;
    if (i >= n4) return;
    const float4 v = ((const float4*)in)[i];
    us4 o; o.x = f2b(v.x); o.y = f2b(v.y); o.z = f2b(v.z); o.w = f2b(v.w);
    ((us4*)out)[i] = o;
}

// ---------------------------------------------------------------------------
// MFMA GEMM: C = A(MxK) @ Bt(NxK)^T + bias. 128x128, BK=64, 4 waves.
// global_load_lds staging (width 16) into unpadded LDS (m97 structure).
// Bias select supports merged QV (col<bN -> bias, else bias2[col-bN]).
// ---------------------------------------------------------------------------
template<int OUT_BF16, int RELU>
__global__ __launch_bounds__(256) void gemm_bt(
    const ushort_t* __restrict__ A, const ushort_t* __restrict__ Bt,
    const float* __restrict__ bias, const float* __restrict__ bias2, int bN,
    void* __restrict__ C, int K, int N)
{
    __shared__ ushort_t As[128*64];
    __shared__ ushort_t Bs[128*64];
    const int tid  = threadIdx.x;
    const int lane = tid & 63, wave = tid >> 6;
    const int wm = wave >> 1, wn = wave & 1;
    const int n = lane & 15, quad = lane >> 4;
    const int bm = blockIdx.y * 128, bn = blockIdx.x * 128;

    f32x4 acc[4][4];
    #pragma unroll
    for (int i = 0; i < 4; ++i)
        #pragma unroll
        for (int j = 0; j < 4; ++j) acc[i][j] = (f32x4){0.f, 0.f, 0.f, 0.f};

    for (int k0 = 0; k0 < K; k0 += 64) {
        #pragma unroll
        for (int it = 0; it < 4; ++it) {
            const int u   = (it*4 + wave)*64 + lane;   // 16B unit, 0..1023
            const int row = u >> 3, c16 = u & 7;
            gload16(A  + (size_t)(bm + row) * K + k0 + c16*8, (char*)As + (it*4 + wave)*1024);
            gload16(Bt + (size_t)(bn + row) * K + k0 + c16*8, (char*)Bs + (it*4 + wave)*1024);
        }
        __syncthreads();
        #pragma unroll
        for (int ks = 0; ks < 2; ++ks) {
            short8 af[4], bf[4];
            #pragma unroll
            for (int i = 0; i < 4; ++i) af[i] = *(short8*)&As[(wm*64 + i*16 + n)*64 + ks*32 + quad*8];
            #pragma unroll
            for (int j = 0; j < 4; ++j) bf[j] = *(short8*)&Bs[(wn*64 + j*16 + n)*64 + ks*32 + quad*8];
            #pragma unroll
            for (int i = 0; i < 4; ++i)
                #pragma unroll
                for (int j = 0; j < 4; ++j)
                    acc[i][j] = __builtin_amdgcn_mfma_f32_16x16x32_bf16(af[i], bf[j], acc[i][j], 0, 0, 0);
        }
        __syncthreads();
    }
    #pragma unroll
    for (int j = 0; j < 4; ++j) {
        const int col = bn + wn*64 + j*16 + n;
        const float bsv = (col < bN) ? bias[col] : bias2[col - bN];
        #pragma unroll
        for (int i = 0; i < 4; ++i) {
            const int row = bm + wm*64 + i*16 + quad*4;
            #pragma unroll
            for (int r = 0; r < 4; ++r) {
                float v = acc[i][j][r] + bsv;
                if (RELU) v = fmaxf(v, 0.f);
                if (OUT_BF16) ((ushort_t*)C)[(size_t)(row + r) * N + col] = f2b(v);
                else          ((float*)C)[(size_t)(row + r) * N + col]    = v;
            }
        }
    }
}

// ---------------------------------------------------------------------------
// Attention scores: one block per packed causal tile (grid NPAIR, H, B).
// E = exp(scale*QK^T) (masked -> 0) written to packed buffer; column sums
// via global atomics. No max-subtraction (softmax shift-invariant; |s|<~40).
// ---------------------------------------------------------------------------
__global__ __launch_bounds__(256) void attn_scores(
    const ushort_t* __restrict__ QV, const int* __restrict__ amask,
    ushort_t* __restrict__ E, float* __restrict__ lsum)
{
    __shared__ ushort_t Qs[64*96];
    __shared__ ushort_t Ks[64*96];
    __shared__ float padf[64];
    const int tid = threadIdx.x, lane = tid & 63, wave = tid >> 6;
    const int n = lane & 15, quad = lane >> 4;
    const int t = blockIdx.x;
    int qt = (int)((-1.f + sqrtf(1.f + 8.f*(float)t)) * 0.5f);
    if ((qt+1)*(qt+2)/2 <= t) ++qt;
    if (qt*(qt+1)/2 > t) --qt;
    const int kt = t - qt*(qt+1)/2;
    const int q0 = qt*64, k0 = kt*64;
    const int h = blockIdx.y, b = blockIdx.z;
    const ushort_t* Qh = QV + (size_t)b*SS*QVW + h*DKK;
    const ushort_t* Kh = QV + (size_t)b*SS*QVW + DD + h*DKK;

    #pragma unroll
    for (int it = 0; it < 3; ++it) {
        const int u = (it*4 + wave)*64 + lane;     // 16B unit, 0..767
        const int row = u / 12, c16 = u % 12;
        gload16(Qh + (size_t)(q0 + row)*QVW + c16*8, (char*)Qs + (it*4 + wave)*1024);
        gload16(Kh + (size_t)(k0 + row)*QVW + c16*8, (char*)Ks + (it*4 + wave)*1024);
    }
    if (tid < 64) padf[tid] = (amask[b*SS + q0 + tid] != 0) ? 1.f : 0.f;
    __syncthreads();

    ushort_t* Et = E + (size_t)(b*HH + h)*NPAIR*4096 + (size_t)(qt*(qt+1)/2 + kt)*4096;
    float* lb = lsum + (size_t)(b*HH + h)*SS;

    #pragma unroll
    for (int ns = 0; ns < 4; ++ns) {
        f32x4 sa = (f32x4){0.f, 0.f, 0.f, 0.f};
        #pragma unroll
        for (int ks = 0; ks < 3; ++ks) {
            const short8 aq = *(short8*)&Qs[(wave*16 + n)*96 + ks*32 + quad*8];
            const short8 bk = *(short8*)&Ks[(ns*16 + n)*96 + ks*32 + quad*8];
            sa = __builtin_amdgcn_mfma_f32_16x16x32_bf16(aq, bk, sa, 0, 0, 0);
        }
        const int kl = ns*16 + n;
        const int keyg = k0 + kl;
        float s = 0.f;
        #pragma unroll
        for (int r = 0; r < 4; ++r) {
            const int qrow = wave*16 + quad*4 + r;
            const bool dead = (padf[qrow] != 0.f) || (keyg > q0 + qrow);
            const float e = dead ? 0.f : __expf(sa[r] * SM_SCALE);
            s += e;
            Et[qrow * 64 + kl] = f2b(e);
        }
        s += __shfl_xor(s, 16);
        s += __shfl_xor(s, 32);
        if (quad == 0) atomicAdd(&lb[k0 + kl], s);
    }
}

// ---------------------------------------------------------------------------
// V' transpose+scale: QV's KV half -> (B,H,DK,S) bf16 scaled by 1/l_k.
// grid (S/64, H, B).
// ---------------------------------------------------------------------------
__global__ __launch_bounds__(256) void transpose_scale(
    const ushort_t* __restrict__ QV, const float* __restrict__ lsum,
    ushort_t* __restrict__ Vt)
{
    __shared__ ushort_t T[64][104];
    __shared__ float rlv[64];
    const int tid = threadIdx.x;
    const int k0 = blockIdx.x * 64, h = blockIdx.y, b = blockIdx.z;
    const ushort_t* src = QV + (size_t)b*SS*QVW + DD + h*DKK;
    for (int s = tid; s < 768; s += 256) {
        const int r = s / 12, c = s % 12;
        *(short8*)&T[r][c*8] = *(const short8*)(src + (size_t)(k0 + r)*QVW + c*8);
    }
    if (tid < 64) {
        const float l = lsum[(size_t)(b*HH + h)*SS + k0 + tid];
        rlv[tid] = (l > 0.f) ? (1.f / l) : 0.f;
    }
    __syncthreads();
    ushort_t* dst = Vt + ((size_t)b*HH + h)*DKK*SS;
    for (int s = tid; s < 768; s += 256) {
        const int dk = s >> 3, c = s & 7;
        short8 v;
        #pragma unroll
        for (int i = 0; i < 8; ++i)
            v[i] = (short)f2b(b2f(T[c*8 + i][dk]) * rlv[c*8 + i]);
        *(short8*)(dst + (size_t)dk*SS + k0 + c*8) = v;
    }
}

// ---------------------------------------------------------------------------
// PV: O = E @ V'. Barrier-free — E and V' fragments both k-contiguous in
// global, read directly as b128. DK split 96 -> 2x48. grid (16, H, B):
// x = px*2+dh, block does q-tile pair {px, 15-px}, dk half dh.
// ---------------------------------------------------------------------------
__global__ __launch_bounds__(256) void attn_pv(
    const ushort_t* __restrict__ E, const ushort_t* __restrict__ Vt,
    float* __restrict__ O)
{
    const int tid = threadIdx.x, lane = tid & 63, wave = tid >> 6;
    const int n = lane & 15, quad = lane >> 4;
    const int px = blockIdx.x >> 1, dh = blockIdx.x & 1;
    const int h = blockIdx.y, b = blockIdx.z;
    const ushort_t* Eb  = E + (size_t)(b*HH + h)*NPAIR*4096;
    const ushort_t* Vth = Vt + ((size_t)b*HH + h)*DKK*SS + (size_t)dh*48*SS;

    #pragma unroll
    for (int half = 0; half < 2; ++half) {
        const int qt = half ? (15 - px) : px;
        const int q0 = qt * 64;
        f32x4 acc[3];
        #pragma unroll
        for (int t = 0; t < 3; ++t) acc[t] = (f32x4){0.f, 0.f, 0.f, 0.f};
        const ushort_t* Erow = Eb + (size_t)(qt*(qt+1)/2)*4096 + (wave*16 + n)*64;

        for (int kt = 0; kt <= qt; ++kt) {
            #pragma unroll
            for (int kk = 0; kk < 2; ++kk) {
                const short8 ae = *(const short8*)(Erow + (size_t)kt*4096 + kk*32 + quad*8);
                #pragma unroll
                for (int nt = 0; nt < 3; ++nt) {
                    const short8 bv = *(const short8*)(Vth + (size_t)(nt*16 + n)*SS + kt*64 + kk*32 + quad*8);
                    acc[nt] = __builtin_amdgcn_mfma_f32_16x16x32_bf16(ae, bv, acc[nt], 0, 0, 0);
                }
            }
        }
        #pragma unroll
        for (int nt = 0; nt < 3; ++nt) {
            #pragma unroll
            for (int r = 0; r < 4; ++r) {
                const int q = q0 + wave*16 + quad*4 + r;
                O[((size_t)b*SS + q)*DD + h*DKK + dh*48 + nt*16 + n] = acc[nt][r];
            }
        }
    }
}

// ---------------------------------------------------------------------------
// Residual + LayerNorm (+ optional bf16 copy). One block per row.
// ---------------------------------------------------------------------------
__device__ __forceinline__ float block_sum256(float s, float* tmp4)
{
    #pragma unroll
    for (int off = 32; off > 0; off >>= 1) s += __shfl_down(s, off);
    __syncthreads();
    if ((threadIdx.x & 63) == 0) tmp4[threadIdx.x >> 6] = s;
    __syncthreads();
    return tmp4[0] + tmp4[1] + tmp4[2] + tmp4[3];
}

__global__ __launch_bounds__(256) void resid_ln(
    const float* __restrict__ X, const float* __restrict__ R,
    const float* __restrict__ g, const float* __restrict__ beta,
    float* __restrict__ Out, ushort_t* __restrict__ OutB)
{
    __shared__ float tmp4[4];
    const int row = blockIdx.x;
    const int tid = threadIdx.x;
    const float* xp = X + (size_t)row * DD;
    const float* rp = R + (size_t)row * DD;
    float v[3], s = 0.f;
    #pragma unroll
    for (int i = 0; i < 3; ++i) {
        v[i] = xp[tid + 256*i] + rp[tid + 256*i];
        s += v[i];
    }
    const float mu = block_sum256(s, tmp4) * (1.f / DD);
    float qv = 0.f;
    #pragma unroll
    for (int i = 0; i < 3; ++i) { const float d = v[i] - mu; qv += d * d; }
    const float inv = rsqrtf(block_sum256(qv, tmp4) * (1.f / DD) + 1e-5f);
    #pragma unroll
    for (int i = 0; i < 3; ++i) {
        const int c = tid + 256*i;
        const float o = (v[i] - mu) * inv * g[c] + beta[c];
        Out[(size_t)row * DD + c] = o;
        if (OutB) OutB[(size_t)row * DD + c] = f2b(o);
    }
}

// ---------------------------------------------------------------------------
extern "C" void kernel_launch(void* const* d_in, const int* in_sizes, int n_in,
                              void* d_out, int out_size, void* d_ws, size_t ws_size,
                              hipStream_t stream)
{
    (void)in_sizes; (void)n_in; (void)out_size; (void)ws_size;
    const float* x0    = (const float*)d_in[0];
    const int*   amask = (const int*)d_in[1];
    const float* a1_Wq = (const float*)d_in[2];
    const float* a1_bq = (const float*)d_in[3];
    const float* a1_Wv = (const float*)d_in[4];
    const float* a1_bv = (const float*)d_in[5];
    const float* a1_g  = (const float*)d_in[6];
    const float* a1_b  = (const float*)d_in[7];
    const float* a2_Wq = (const float*)d_in[8];
    const float* a2_bq = (const float*)d_in[9];
    const float* a2_Wv = (const float*)d_in[10];
    const float* a2_bv = (const float*)d_in[11];
    const float* a2_g  = (const float*)d_in[12];
    const float* a2_b  = (const float*)d_in[13];
    const float* f_W1  = (const float*)d_in[14];
    const float* f_b1  = (const float*)d_in[15];
    const float* f_W2  = (const float*)d_in[16];
    const float* f_b2  = (const float*)d_in[17];
    const float* f_g   = (const float*)d_in[18];
    const float* f_b   = (const float*)d_in[19];

    char* ws = (char*)d_ws;
    size_t off = 0;
    auto alloc = [&](size_t bytes) { void* p = ws + off; off += (bytes + 255) & ~(size_t)255; return p; };
    ushort_t* WqvT1 = (ushort_t*)alloc((size_t)QVW*DD*2);   // rows 0..767 Wq^T, 768..1535 Wv^T
    ushort_t* WqvT2 = (ushort_t*)alloc((size_t)QVW*DD*2);
    ushort_t* W1T   = (ushort_t*)alloc((size_t)DD*FFF*2);
    ushort_t* W2T   = (ushort_t*)alloc((size_t)DD*FFF*2);
    ushort_t* xb    = (ushort_t*)alloc((size_t)MM*DD*2);
    ushort_t* QVb   = (ushort_t*)alloc((size_t)MM*QVW*2);   // Q | KV merged; aliased as hb
    ushort_t* hb    = QVb;                                  // M x FF bf16 (16.8MB < 25.2MB)
    ushort_t* Vtb   = (ushort_t*)alloc((size_t)MM*DD*2);    // (B,H,DK,S)
    float* t0  = (float*)alloc((size_t)MM*DD*4);
    float* lst = (float*)alloc((size_t)BB*HH*SS*4);
    ushort_t* Ebuf = (ushort_t*)alloc((size_t)BB*HH*NPAIR*4096*2);   // 71.3 MB
    float* out = (float*)d_out;

    const dim3 blk(256);
    const dim3 gsc(NPAIR, HH, BB);
    const dim3 gpv(NTILES, HH, BB);
    const dim3 gtr(SS/64, HH, BB);
    const dim3 gqv(QVW/128, MM/128);
    const dim3 gf1(FFF/128, MM/128);
    const dim3 gf2(DD/128, MM/128);
    const int  nL = BB*HH*SS;

    castWT<<<dim3(DD/32, DD/32),  blk, 0, stream>>>(a1_Wq, WqvT1, DD, DD);
    castWT<<<dim3(DD/32, DD/32),  blk, 0, stream>>>(a1_Wv, WqvT1 + (size_t)DD*DD, DD, DD);
    castWT<<<dim3(DD/32, DD/32),  blk, 0, stream>>>(a2_Wq, WqvT2, DD, DD);
    castWT<<<dim3(DD/32, DD/32),  blk, 0, stream>>>(a2_Wv, WqvT2 + (size_t)DD*DD, DD, DD);
    castWT<<<dim3(FFF/32, DD/32), blk, 0, stream>>>(f_W1,  W1T,  DD, FFF);
    castWT<<<dim3(DD/32, FFF/32), blk, 0, stream>>>(f_W2,  W2T,  FFF, DD);
    cast_f2b<<<(MM*DD/4 + 255)/256, blk, 0, stream>>>(x0, xb, MM*DD/4);

    // ---- layer 1 ----
    gemm_bt<1,0><<<gqv, blk, 0, stream>>>(xb, WqvT1, a1_bq, a1_bv, DD, QVb, DD, QVW);
    zerof<<<(nL + 255)/256, blk, 0, stream>>>(lst, nL);
    attn_scores<<<gsc, blk, 0, stream>>>(QVb, amask, Ebuf, lst);
    transpose_scale<<<gtr, blk, 0, stream>>>(QVb, lst, Vtb);
    attn_pv<<<gpv, blk, 0, stream>>>(Ebuf, Vtb, t0);
    resid_ln<<<dim3(MM), blk, 0, stream>>>(t0, x0, a1_g, a1_b, t0, xb);      // x1

    // ---- layer 2 ----
    gemm_bt<1,0><<<gqv, blk, 0, stream>>>(xb, WqvT2, a2_bq, a2_bv, DD, QVb, DD, QVW);
    zerof<<<(nL + 255)/256, blk, 0, stream>>>(lst, nL);
    attn_scores<<<gsc, blk, 0, stream>>>(QVb, amask, Ebuf, lst);
    transpose_scale<<<gtr, blk, 0, stream>>>(QVb, lst, Vtb);
    attn_pv<<<gpv, blk, 0, stream>>>(Ebuf, Vtb, out);
    resid_ln<<<dim3(MM), blk, 0, stream>>>(out, t0, a2_g, a2_b, out, xb);    // x2

    // ---- FFN ----
    gemm_bt<1,1><<<gf1, blk, 0, stream>>>(xb, W1T, f_b1, f_b1, FFF, hb, DD, FFF);
    gemm_bt<0,0><<<gf2, blk, 0, stream>>>(hb, W2T, f_b2, f_b2, DD, t0, FFF, DD);
    resid_ln<<<dim3(MM), blk, 0, stream>>>(t0, out, f_g, f_b, out, (ushort_t*)nullptr);
}

// Round 5
// 463.194 us; speedup vs baseline: 1.1338x; 1.1338x over previous
//
#include <hip/hip_runtime.h>
#include <cstddef>

#define BB 8
#define SS 1024
#define DD 768
#define HH 8
#define DKK 96
#define FFF 1024
#define MM (BB*SS)
#define QVW 1536                       // merged Q|KV row width
#define SM_SCALE 0.10206207261596577f  // 1/sqrt(96)
#define NTILES 16
#define NPAIR  136                     // 16*17/2 packed causal tiles

typedef unsigned short ushort_t;
typedef short short8 __attribute__((ext_vector_type(8)));
typedef float f32x4 __attribute__((ext_vector_type(4)));
typedef ushort_t us4 __attribute__((ext_vector_type(4)));

__device__ __forceinline__ ushort_t f2b(float f) {
    union { float f; unsigned u; } x; x.f = f;
    unsigned r = x.u + 0x7fffu + ((x.u >> 16) & 1u);   // RNE
    return (ushort_t)(r >> 16);
}
__device__ __forceinline__ float b2f(ushort_t u) {
    union { unsigned u; float f; } x; x.u = ((unsigned)u) << 16;
    return x.f;
}
// async global->LDS, 16B per lane; LDS dest = wave-uniform base + lane*16
__device__ __forceinline__ void gload16(const ushort_t* g, void* lds_base) {
    __builtin_amdgcn_global_load_lds(
        (const __attribute__((address_space(1))) unsigned int*)g,
        (__attribute__((address_space(3))) unsigned int*)lds_base, 16, 0, 0);
}

// ---------------------------------------------------------------------------
__global__ __launch_bounds__(256) void zerof(float* __restrict__ p, int n)
{
    const int i = blockIdx.x * 256 + threadIdx.x;
    if (i < n) p[i] = 0.f;
}

// Weight cast+transpose: W (KxN fp32) -> Wt (NxK bf16). grid (N/32, K/32).
__global__ __launch_bounds__(256) void castWT(
    const float* __restrict__ W, ushort_t* __restrict__ Wt, int K, int N)
{
    __shared__ float T[32][33];
    const int tx = threadIdx.x & 31, ty = threadIdx.x >> 5;
    const int n0 = blockIdx.x * 32, k0 = blockIdx.y * 32;
    #pragma unroll
    for (int r = 0; r < 4; ++r)
        T[ty + 8*r][tx] = W[(size_t)(k0 + ty + 8*r) * N + n0 + tx];
    __syncthreads();
    #pragma unroll
    for (int r = 0; r < 4; ++r)
        Wt[(size_t)(n0 + ty + 8*r) * K + k0 + tx] = f2b(T[tx][ty + 8*r]);
}

__global__ __launch_bounds__(256) void cast_f2b(
    const float* __restrict__ in, ushort_t* __restrict__ out, int n4)
{
    const int i = blockIdx.x * 256 + threadIdx.x;
    if (i >= n4) return;
    const float4 v = ((const float4*)in)[i];
    us4 o; o.x = f2b(v.x); o.y = f2b(v.y); o.z = f2b(v.z); o.w = f2b(v.w);
    ((us4*)out)[i] = o;
}

// ---------------------------------------------------------------------------
// MFMA GEMM: C = A(MxK) @ Bt(NxK)^T + bias. 128x128, BK=64, 4 waves.
// global_load_lds staging (width 16) into unpadded LDS (m97 structure).
// Bias select supports merged QV (col<bN -> bias, else bias2[col-bN]).
// ---------------------------------------------------------------------------
template<int OUT_BF16, int RELU>
__global__ __launch_bounds__(256) void gemm_bt(
    const ushort_t* __restrict__ A, const ushort_t* __restrict__ Bt,
    const float* __restrict__ bias, const float* __restrict__ bias2, int bN,
    void* __restrict__ C, int K, int N)
{
    __shared__ ushort_t As[128*64];
    __shared__ ushort_t Bs[128*64];
    const int tid  = threadIdx.x;
    const int lane = tid & 63, wave = tid >> 6;
    const int wm = wave >> 1, wn = wave & 1;
    const int n = lane & 15, quad = lane >> 4;
    const int bm = blockIdx.y * 128, bn = blockIdx.x * 128;

    f32x4 acc[4][4];
    #pragma unroll
    for (int i = 0; i < 4; ++i)
        #pragma unroll
        for (int j = 0; j < 4; ++j) acc[i][j] = (f32x4){0.f, 0.f, 0.f, 0.f};

    for (int k0 = 0; k0 < K; k0 += 64) {
        #pragma unroll
        for (int it = 0; it < 4; ++it) {
            const int u   = (it*4 + wave)*64 + lane;   // 16B unit, 0..1023
            const int row = u >> 3, c16 = u & 7;
            gload16(A  + (size_t)(bm + row) * K + k0 + c16*8, (char*)As + (it*4 + wave)*1024);
            gload16(Bt + (size_t)(bn + row) * K + k0 + c16*8, (char*)Bs + (it*4 + wave)*1024);
        }
        __syncthreads();
        #pragma unroll
        for (int ks = 0; ks < 2; ++ks) {
            short8 af[4], bf[4];
            #pragma unroll
            for (int i = 0; i < 4; ++i) af[i] = *(short8*)&As[(wm*64 + i*16 + n)*64 + ks*32 + quad*8];
            #pragma unroll
            for (int j = 0; j < 4; ++j) bf[j] = *(short8*)&Bs[(wn*64 + j*16 + n)*64 + ks*32 + quad*8];
            #pragma unroll
            for (int i = 0; i < 4; ++i)
                #pragma unroll
                for (int j = 0; j < 4; ++j)
                    acc[i][j] = __builtin_amdgcn_mfma_f32_16x16x32_bf16(af[i], bf[j], acc[i][j], 0, 0, 0);
        }
        __syncthreads();
    }
    #pragma unroll
    for (int j = 0; j < 4; ++j) {
        const int col = bn + wn*64 + j*16 + n;
        const float bsv = (col < bN) ? bias[col] : bias2[col - bN];
        #pragma unroll
        for (int i = 0; i < 4; ++i) {
            const int row = bm + wm*64 + i*16 + quad*4;
            #pragma unroll
            for (int r = 0; r < 4; ++r) {
                float v = acc[i][j][r] + bsv;
                if (RELU) v = fmaxf(v, 0.f);
                if (OUT_BF16) ((ushort_t*)C)[(size_t)(row + r) * N + col] = f2b(v);
                else          ((float*)C)[(size_t)(row + r) * N + col]    = v;
            }
        }
    }
}

// ---------------------------------------------------------------------------
// Attention scores: one block per packed causal tile (grid NPAIR, H, B).
// E = exp(scale*QK^T) (masked -> 0) written to packed buffer; column sums
// via global atomics. No max-subtraction (softmax shift-invariant; |s|<~40).
// ---------------------------------------------------------------------------
__global__ __launch_bounds__(256) void attn_scores(
    const ushort_t* __restrict__ QV, const int* __restrict__ amask,
    ushort_t* __restrict__ E, float* __restrict__ lsum)
{
    __shared__ ushort_t Qs[64*96];
    __shared__ ushort_t Ks[64*96];
    __shared__ float padf[64];
    const int tid = threadIdx.x, lane = tid & 63, wave = tid >> 6;
    const int n = lane & 15, quad = lane >> 4;
    const int t = blockIdx.x;
    int qt = (int)((-1.f + sqrtf(1.f + 8.f*(float)t)) * 0.5f);
    if ((qt+1)*(qt+2)/2 <= t) ++qt;
    if (qt*(qt+1)/2 > t) --qt;
    const int kt = t - qt*(qt+1)/2;
    const int q0 = qt*64, k0 = kt*64;
    const int h = blockIdx.y, b = blockIdx.z;
    const ushort_t* Qh = QV + (size_t)b*SS*QVW + h*DKK;
    const ushort_t* Kh = QV + (size_t)b*SS*QVW + DD + h*DKK;

    #pragma unroll
    for (int it = 0; it < 3; ++it) {
        const int u = (it*4 + wave)*64 + lane;     // 16B unit, 0..767
        const int row = u / 12, c16 = u % 12;
        gload16(Qh + (size_t)(q0 + row)*QVW + c16*8, (char*)Qs + (it*4 + wave)*1024);
        gload16(Kh + (size_t)(k0 + row)*QVW + c16*8, (char*)Ks + (it*4 + wave)*1024);
    }
    if (tid < 64) padf[tid] = (amask[b*SS + q0 + tid] != 0) ? 1.f : 0.f;
    __syncthreads();

    ushort_t* Et = E + (size_t)(b*HH + h)*NPAIR*4096 + (size_t)(qt*(qt+1)/2 + kt)*4096;
    float* lb = lsum + (size_t)(b*HH + h)*SS;

    #pragma unroll
    for (int ns = 0; ns < 4; ++ns) {
        f32x4 sa = (f32x4){0.f, 0.f, 0.f, 0.f};
        #pragma unroll
        for (int ks = 0; ks < 3; ++ks) {
            const short8 aq = *(short8*)&Qs[(wave*16 + n)*96 + ks*32 + quad*8];
            const short8 bk = *(short8*)&Ks[(ns*16 + n)*96 + ks*32 + quad*8];
            sa = __builtin_amdgcn_mfma_f32_16x16x32_bf16(aq, bk, sa, 0, 0, 0);
        }
        const int kl = ns*16 + n;
        const int keyg = k0 + kl;
        float s = 0.f;
        #pragma unroll
        for (int r = 0; r < 4; ++r) {
            const int qrow = wave*16 + quad*4 + r;
            const bool dead = (padf[qrow] != 0.f) || (keyg > q0 + qrow);
            const float e = dead ? 0.f : __expf(sa[r] * SM_SCALE);
            s += e;
            Et[qrow * 64 + kl] = f2b(e);
        }
        s += __shfl_xor(s, 16);
        s += __shfl_xor(s, 32);
        if (quad == 0) atomicAdd(&lb[k0 + kl], s);
    }
}

// ---------------------------------------------------------------------------
// V' transpose+scale: QV's KV half -> (B,H,DK,S) bf16 scaled by 1/l_k.
// grid (S/64, H, B).
// ---------------------------------------------------------------------------
__global__ __launch_bounds__(256) void transpose_scale(
    const ushort_t* __restrict__ QV, const float* __restrict__ lsum,
    ushort_t* __restrict__ Vt)
{
    __shared__ ushort_t T[64][104];
    __shared__ float rlv[64];
    const int tid = threadIdx.x;
    const int k0 = blockIdx.x * 64, h = blockIdx.y, b = blockIdx.z;
    const ushort_t* src = QV + (size_t)b*SS*QVW + DD + h*DKK;
    for (int s = tid; s < 768; s += 256) {
        const int r = s / 12, c = s % 12;
        *(short8*)&T[r][c*8] = *(const short8*)(src + (size_t)(k0 + r)*QVW + c*8);
    }
    if (tid < 64) {
        const float l = lsum[(size_t)(b*HH + h)*SS + k0 + tid];
        rlv[tid] = (l > 0.f) ? (1.f / l) : 0.f;
    }
    __syncthreads();
    ushort_t* dst = Vt + ((size_t)b*HH + h)*DKK*SS;
    for (int s = tid; s < 768; s += 256) {
        const int dk = s >> 3, c = s & 7;
        short8 v;
        #pragma unroll
        for (int i = 0; i < 8; ++i)
            v[i] = (short)f2b(b2f(T[c*8 + i][dk]) * rlv[c*8 + i]);
        *(short8*)(dst + (size_t)dk*SS + k0 + c*8) = v;
    }
}

// ---------------------------------------------------------------------------
// PV: O = E @ V'. LDS-staged MFMA GEMM (m97 structure): per k-tile stage
// E tile (64x64, contiguous 8KB) + V' tile (96 rows x 64 keys, 12KB) via
// global_load_lds, then 12 MFMAs/wave. Causal pair {px, 15-px} for uniform
// work (17 k-tiles/block); grid (8, H, B). E read once.
// ---------------------------------------------------------------------------
__global__ __launch_bounds__(256) void attn_pv(
    const ushort_t* __restrict__ E, const ushort_t* __restrict__ Vt,
    float* __restrict__ O)
{
    __shared__ ushort_t Es[64*64];    // 8 KB
    __shared__ ushort_t Vs[96*64];    // 12 KB
    const int tid = threadIdx.x, lane = tid & 63, wave = tid >> 6;
    const int n = lane & 15, quad = lane >> 4;
    const int px = blockIdx.x;
    const int h = blockIdx.y, b = blockIdx.z;
    const ushort_t* Eb  = E + (size_t)(b*HH + h)*NPAIR*4096;
    const ushort_t* Vth = Vt + ((size_t)b*HH + h)*DKK*SS;

    #pragma unroll
    for (int half = 0; half < 2; ++half) {
        const int qt = half ? (15 - px) : px;
        const int q0 = qt * 64;
        f32x4 acc[6];
        #pragma unroll
        for (int t = 0; t < 6; ++t) acc[t] = (f32x4){0.f, 0.f, 0.f, 0.f};
        const ushort_t* Eq = Eb + (size_t)(qt*(qt+1)/2)*4096;

        for (int kt = 0; kt <= qt; ++kt) {
            // E tile: 4096 ushorts contiguous = 512 x 16B units
            const ushort_t* Et = Eq + (size_t)kt*4096;
            #pragma unroll
            for (int it = 0; it < 2; ++it)
                gload16(Et + ((it*4 + wave)*64 + lane)*8, (char*)Es + (it*4 + wave)*1024);
            // V' tile: 96 rows x 128B; each wave-pass stages 8 rows (1KB)
            #pragma unroll
            for (int it = 0; it < 3; ++it) {
                const int r8 = it*4 + wave;                    // 0..11
                const int row = r8*8 + (lane >> 3), c16 = lane & 7;
                gload16(Vth + (size_t)row*SS + kt*64 + c16*8, (char*)Vs + r8*1024);
            }
            __syncthreads();
            #pragma unroll
            for (int kk = 0; kk < 2; ++kk) {
                const short8 ae = *(short8*)&Es[(wave*16 + n)*64 + kk*32 + quad*8];
                #pragma unroll
                for (int nt = 0; nt < 6; ++nt) {
                    const short8 bv = *(short8*)&Vs[(nt*16 + n)*64 + kk*32 + quad*8];
                    acc[nt] = __builtin_amdgcn_mfma_f32_16x16x32_bf16(ae, bv, acc[nt], 0, 0, 0);
                }
            }
            __syncthreads();
        }
        #pragma unroll
        for (int nt = 0; nt < 6; ++nt) {
            #pragma unroll
            for (int r = 0; r < 4; ++r) {
                const int q = q0 + wave*16 + quad*4 + r;
                O[((size_t)b*SS + q)*DD + h*DKK + nt*16 + n] = acc[nt][r];
            }
        }
    }
}

// ---------------------------------------------------------------------------
// Residual + LayerNorm (+ optional bf16 copy). One block per row.
// ---------------------------------------------------------------------------
__device__ __forceinline__ float block_sum256(float s, float* tmp4)
{
    #pragma unroll
    for (int off = 32; off > 0; off >>= 1) s += __shfl_down(s, off);
    __syncthreads();
    if ((threadIdx.x & 63) == 0) tmp4[threadIdx.x >> 6] = s;
    __syncthreads();
    return tmp4[0] + tmp4[1] + tmp4[2] + tmp4[3];
}

__global__ __launch_bounds__(256) void resid_ln(
    const float* __restrict__ X, const float* __restrict__ R,
    const float* __restrict__ g, const float* __restrict__ beta,
    float* __restrict__ Out, ushort_t* __restrict__ OutB)
{
    __shared__ float tmp4[4];
    const int row = blockIdx.x;
    const int tid = threadIdx.x;
    const float* xp = X + (size_t)row * DD;
    const float* rp = R + (size_t)row * DD;
    float v[3], s = 0.f;
    #pragma unroll
    for (int i = 0; i < 3; ++i) {
        v[i] = xp[tid + 256*i] + rp[tid + 256*i];
        s += v[i];
    }
    const float mu = block_sum256(s, tmp4) * (1.f / DD);
    float qv = 0.f;
    #pragma unroll
    for (int i = 0; i < 3; ++i) { const float d = v[i] - mu; qv += d * d; }
    const float inv = rsqrtf(block_sum256(qv, tmp4) * (1.f / DD) + 1e-5f);
    #pragma unroll
    for (int i = 0; i < 3; ++i) {
        const int c = tid + 256*i;
        const float o = (v[i] - mu) * inv * g[c] + beta[c];
        Out[(size_t)row * DD + c] = o;
        if (OutB) OutB[(size_t)row * DD + c] = f2b(o);
    }
}

// ---------------------------------------------------------------------------
extern "C" void kernel_launch(void* const* d_in, const int* in_sizes, int n_in,
                              void* d_out, int out_size, void* d_ws, size_t ws_size,
                              hipStream_t stream)
{
    (void)in_sizes; (void)n_in; (void)out_size; (void)ws_size;
    const float* x0    = (const float*)d_in[0];
    const int*   amask = (const int*)d_in[1];
    const float* a1_Wq = (const float*)d_in[2];
    const float* a1_bq = (const float*)d_in[3];
    const float* a1_Wv = (const float*)d_in[4];
    const float* a1_bv = (const float*)d_in[5];
    const float* a1_g  = (const float*)d_in[6];
    const float* a1_b  = (const float*)d_in[7];
    const float* a2_Wq = (const float*)d_in[8];
    const float* a2_bq = (const float*)d_in[9];
    const float* a2_Wv = (const float*)d_in[10];
    const float* a2_bv = (const float*)d_in[11];
    const float* a2_g  = (const float*)d_in[12];
    const float* a2_b  = (const float*)d_in[13];
    const float* f_W1  = (const float*)d_in[14];
    const float* f_b1  = (const float*)d_in[15];
    const float* f_W2  = (const float*)d_in[16];
    const float* f_b2  = (const float*)d_in[17];
    const float* f_g   = (const float*)d_in[18];
    const float* f_b   = (const float*)d_in[19];

    char* ws = (char*)d_ws;
    size_t off = 0;
    auto alloc = [&](size_t bytes) { void* p = ws + off; off += (bytes + 255) & ~(size_t)255; return p; };
    ushort_t* WqvT1 = (ushort_t*)alloc((size_t)QVW*DD*2);   // rows 0..767 Wq^T, 768..1535 Wv^T
    ushort_t* WqvT2 = (ushort_t*)alloc((size_t)QVW*DD*2);
    ushort_t* W1T   = (ushort_t*)alloc((size_t)DD*FFF*2);
    ushort_t* W2T   = (ushort_t*)alloc((size_t)DD*FFF*2);
    ushort_t* xb    = (ushort_t*)alloc((size_t)MM*DD*2);
    ushort_t* QVb   = (ushort_t*)alloc((size_t)MM*QVW*2);   // Q | KV merged; aliased as hb
    ushort_t* hb    = QVb;                                  // M x FF bf16 (16.8MB < 25.2MB)
    ushort_t* Vtb   = (ushort_t*)alloc((size_t)MM*DD*2);    // (B,H,DK,S)
    float* t0  = (float*)alloc((size_t)MM*DD*4);
    float* lst = (float*)alloc((size_t)BB*HH*SS*4);
    ushort_t* Ebuf = (ushort_t*)alloc((size_t)BB*HH*NPAIR*4096*2);   // 71.3 MB
    float* out = (float*)d_out;

    const dim3 blk(256);
    const dim3 gsc(NPAIR, HH, BB);
    const dim3 gpv(NTILES/2, HH, BB);
    const dim3 gtr(SS/64, HH, BB);
    const dim3 gqv(QVW/128, MM/128);
    const dim3 gf1(FFF/128, MM/128);
    const dim3 gf2(DD/128, MM/128);
    const int  nL = BB*HH*SS;

    castWT<<<dim3(DD/32, DD/32),  blk, 0, stream>>>(a1_Wq, WqvT1, DD, DD);
    castWT<<<dim3(DD/32, DD/32),  blk, 0, stream>>>(a1_Wv, WqvT1 + (size_t)DD*DD, DD, DD);
    castWT<<<dim3(DD/32, DD/32),  blk, 0, stream>>>(a2_Wq, WqvT2, DD, DD);
    castWT<<<dim3(DD/32, DD/32),  blk, 0, stream>>>(a2_Wv, WqvT2 + (size_t)DD*DD, DD, DD);
    castWT<<<dim3(FFF/32, DD/32), blk, 0, stream>>>(f_W1,  W1T,  DD, FFF);
    castWT<<<dim3(DD/32, FFF/32), blk, 0, stream>>>(f_W2,  W2T,  FFF, DD);
    cast_f2b<<<(MM*DD/4 + 255)/256, blk, 0, stream>>>(x0, xb, MM*DD/4);

    // ---- layer 1 ----
    gemm_bt<1,0><<<gqv, blk, 0, stream>>>(xb, WqvT1, a1_bq, a1_bv, DD, QVb, DD, QVW);
    zerof<<<(nL + 255)/256, blk, 0, stream>>>(lst, nL);
    attn_scores<<<gsc, blk, 0, stream>>>(QVb, amask, Ebuf, lst);
    transpose_scale<<<gtr, blk, 0, stream>>>(QVb, lst, Vtb);
    attn_pv<<<gpv, blk, 0, stream>>>(Ebuf, Vtb, t0);
    resid_ln<<<dim3(MM), blk, 0, stream>>>(t0, x0, a1_g, a1_b, t0, xb);      // x1

    // ---- layer 2 ----
    gemm_bt<1,0><<<gqv, blk, 0, stream>>>(xb, WqvT2, a2_bq, a2_bv, DD, QVb, DD, QVW);
    zerof<<<(nL + 255)/256, blk, 0, stream>>>(lst, nL);
    attn_scores<<<gsc, blk, 0, stream>>>(QVb, amask, Ebuf, lst);
    transpose_scale<<<gtr, blk, 0, stream>>>(QVb, lst, Vtb);
    attn_pv<<<gpv, blk, 0, stream>>>(Ebuf, Vtb, out);
    resid_ln<<<dim3(MM), blk, 0, stream>>>(out, t0, a2_g, a2_b, out, xb);    // x2

    // ---- FFN ----
    gemm_bt<1,1><<<gf1, blk, 0, stream>>>(xb, W1T, f_b1, f_b1, FFF, hb, DD, FFF);
    gemm_bt<0,0><<<gf2, blk, 0, stream>>>(hb, W2T, f_b2, f_b2, DD, t0, FFF, DD);
    resid_ln<<<dim3(MM), blk, 0, stream>>>(t0, out, f_g, f_b, out, (ushort_t*)nullptr);
}

// Round 6
// 441.698 us; speedup vs baseline: 1.1890x; 1.0487x over previous
//
#include <hip/hip_runtime.h>
#include <cstddef>

#define BB 8
#define SS 1024
#define DD 768
#define HH 8
#define DKK 96
#define FFF 1024
#define MM (BB*SS)
#define QVW 1536                       // merged Q|KV row width
#define SM_SCALE 0.10206207261596577f  // 1/sqrt(96)
#define NTILES 16
#define NPAIR  136                     // 16*17/2 packed causal tiles

typedef unsigned short ushort_t;
typedef short short8 __attribute__((ext_vector_type(8)));
typedef float f32x4 __attribute__((ext_vector_type(4)));
typedef ushort_t us4 __attribute__((ext_vector_type(4)));

__device__ __forceinline__ ushort_t f2b(float f) {
    union { float f; unsigned u; } x; x.f = f;
    unsigned r = x.u + 0x7fffu + ((x.u >> 16) & 1u);   // RNE
    return (ushort_t)(r >> 16);
}
__device__ __forceinline__ float b2f(ushort_t u) {
    union { unsigned u; float f; } x; x.u = ((unsigned)u) << 16;
    return x.f;
}
// async global->LDS, 16B per lane; LDS dest = wave-uniform base + lane*16
__device__ __forceinline__ void gload16(const ushort_t* g, void* lds_base) {
    __builtin_amdgcn_global_load_lds(
        (const __attribute__((address_space(1))) unsigned int*)g,
        (__attribute__((address_space(3))) unsigned int*)lds_base, 16, 0, 0);
}

// ---------------------------------------------------------------------------
// Weight cast+transpose: W (KxN fp32) -> Wt (NxK bf16). grid (N/32, K/32).
// ---------------------------------------------------------------------------
__global__ __launch_bounds__(256) void castWT(
    const float* __restrict__ W, ushort_t* __restrict__ Wt, int K, int N)
{
    __shared__ float T[32][33];
    const int tx = threadIdx.x & 31, ty = threadIdx.x >> 5;
    const int n0 = blockIdx.x * 32, k0 = blockIdx.y * 32;
    #pragma unroll
    for (int r = 0; r < 4; ++r)
        T[ty + 8*r][tx] = W[(size_t)(k0 + ty + 8*r) * N + n0 + tx];
    __syncthreads();
    #pragma unroll
    for (int r = 0; r < 4; ++r)
        Wt[(size_t)(n0 + ty + 8*r) * K + k0 + tx] = f2b(T[tx][ty + 8*r]);
}

// 4x DDxDD weights in one launch. grid (DD/32, DD/32, 4).
__global__ __launch_bounds__(256) void castWT4(
    const float* __restrict__ Wa, const float* __restrict__ Wb,
    const float* __restrict__ Wc, const float* __restrict__ Wd,
    ushort_t* __restrict__ Ta, ushort_t* __restrict__ Tb,
    ushort_t* __restrict__ Tc, ushort_t* __restrict__ Td)
{
    __shared__ float T[32][33];
    const float* W; ushort_t* Wt;
    switch (blockIdx.z) {
        case 0:  W = Wa; Wt = Ta; break;
        case 1:  W = Wb; Wt = Tb; break;
        case 2:  W = Wc; Wt = Tc; break;
        default: W = Wd; Wt = Td; break;
    }
    const int tx = threadIdx.x & 31, ty = threadIdx.x >> 5;
    const int n0 = blockIdx.x * 32, k0 = blockIdx.y * 32;
    #pragma unroll
    for (int r = 0; r < 4; ++r)
        T[ty + 8*r][tx] = W[(size_t)(k0 + ty + 8*r) * DD + n0 + tx];
    __syncthreads();
    #pragma unroll
    for (int r = 0; r < 4; ++r)
        Wt[(size_t)(n0 + ty + 8*r) * DD + k0 + tx] = f2b(T[tx][ty + 8*r]);
}

__global__ __launch_bounds__(256) void cast_f2b(
    const float* __restrict__ in, ushort_t* __restrict__ out, int n4)
{
    const int i = blockIdx.x * 256 + threadIdx.x;
    if (i >= n4) return;
    const float4 v = ((const float4*)in)[i];
    us4 o; o.x = f2b(v.x); o.y = f2b(v.y); o.z = f2b(v.z); o.w = f2b(v.w);
    ((us4*)out)[i] = o;
}

// ---------------------------------------------------------------------------
// MFMA GEMM: C = A(MxK) @ Bt(NxK)^T + bias. 128x128, BK=64, 4 waves.
// global_load_lds staging with XOR bank swizzle: chunk c of row r lives at
// LDS unit r*8 + (c ^ (r&7))  -> fragment ds_read_b128 hits 2 lanes/bank.
// ---------------------------------------------------------------------------
template<int OUT_BF16, int RELU>
__global__ __launch_bounds__(256) void gemm_bt(
    const ushort_t* __restrict__ A, const ushort_t* __restrict__ Bt,
    const float* __restrict__ bias, const float* __restrict__ bias2, int bN,
    void* __restrict__ C, int K, int N)
{
    __shared__ ushort_t As[128*64];
    __shared__ ushort_t Bs[128*64];
    const int tid  = threadIdx.x;
    const int lane = tid & 63, wave = tid >> 6;
    const int wm = wave >> 1, wn = wave & 1;
    const int n = lane & 15, quad = lane >> 4;
    const int sx = n & 7;              // read-side swizzle key
    const int bm = blockIdx.y * 128, bn = blockIdx.x * 128;

    f32x4 acc[4][4];
    #pragma unroll
    for (int i = 0; i < 4; ++i)
        #pragma unroll
        for (int j = 0; j < 4; ++j) acc[i][j] = (f32x4){0.f, 0.f, 0.f, 0.f};

    for (int k0 = 0; k0 < K; k0 += 64) {
        #pragma unroll
        for (int it = 0; it < 4; ++it) {
            const int u   = (it*4 + wave)*64 + lane;   // LDS 16B unit, 0..1023
            const int row = u >> 3;
            const int c   = (u & 7) ^ (row & 7);       // swizzled global chunk
            gload16(A  + (size_t)(bm + row) * K + k0 + c*8, (char*)As + (it*4 + wave)*1024);
            gload16(Bt + (size_t)(bn + row) * K + k0 + c*8, (char*)Bs + (it*4 + wave)*1024);
        }
        __syncthreads();
        #pragma unroll
        for (int ks = 0; ks < 2; ++ks) {
            short8 af[4], bf[4];
            #pragma unroll
            for (int i = 0; i < 4; ++i)
                af[i] = *(short8*)&As[((wm*64 + i*16 + n)*8 + ((ks*4 + quad) ^ sx))*8];
            #pragma unroll
            for (int j = 0; j < 4; ++j)
                bf[j] = *(short8*)&Bs[((wn*64 + j*16 + n)*8 + ((ks*4 + quad) ^ sx))*8];
            #pragma unroll
            for (int i = 0; i < 4; ++i)
                #pragma unroll
                for (int j = 0; j < 4; ++j)
                    acc[i][j] = __builtin_amdgcn_mfma_f32_16x16x32_bf16(af[i], bf[j], acc[i][j], 0, 0, 0);
        }
        __syncthreads();
    }
    #pragma unroll
    for (int j = 0; j < 4; ++j) {
        const int col = bn + wn*64 + j*16 + n;
        const float bsv = (col < bN) ? bias[col] : bias2[col - bN];
        #pragma unroll
        for (int i = 0; i < 4; ++i) {
            const int row = bm + wm*64 + i*16 + quad*4;
            #pragma unroll
            for (int r = 0; r < 4; ++r) {
                float v = acc[i][j][r] + bsv;
                if (RELU) v = fmaxf(v, 0.f);
                if (OUT_BF16) ((ushort_t*)C)[(size_t)(row + r) * N + col] = f2b(v);
                else          ((float*)C)[(size_t)(row + r) * N + col]    = v;
            }
        }
    }
}

// ---------------------------------------------------------------------------
// Attention scores: one block per packed causal tile (grid NPAIR, H, B).
// E = exp(scale*QK^T) (masked -> 0) to packed buffer; per-(qt,column) sums
// written non-atomically to lpart[b,h,qt,k]. Rows padded to 16 chunks with
// the same XOR swizzle (invalid chunks skipped via exec mask).
// ---------------------------------------------------------------------------
__global__ __launch_bounds__(256) void attn_scores(
    const ushort_t* __restrict__ QV, const int* __restrict__ amask,
    ushort_t* __restrict__ E, float* __restrict__ lpart)
{
    __shared__ ushort_t Qs[64*128];
    __shared__ ushort_t Ks[64*128];
    __shared__ float colsum[4][64];
    __shared__ float padf[64];
    const int tid = threadIdx.x, lane = tid & 63, wave = tid >> 6;
    const int n = lane & 15, quad = lane >> 4;
    const int sx = n & 7;
    const int t = blockIdx.x;
    int qt = (int)((-1.f + sqrtf(1.f + 8.f*(float)t)) * 0.5f);
    if ((qt+1)*(qt+2)/2 <= t) ++qt;
    if (qt*(qt+1)/2 > t) --qt;
    const int kt = t - qt*(qt+1)/2;
    const int q0 = qt*64, k0 = kt*64;
    const int h = blockIdx.y, b = blockIdx.z;
    const ushort_t* Qh = QV + (size_t)b*SS*QVW + h*DKK;
    const ushort_t* Kh = QV + (size_t)b*SS*QVW + DD + h*DKK;

    #pragma unroll
    for (int it = 0; it < 4; ++it) {
        const int u = (it*4 + wave)*64 + lane;     // LDS unit, 0..1023
        const int row = u >> 4;
        const int c = (u & 15) ^ (row & 7);        // 0..15; valid if <12
        if (c < 12) {
            gload16(Qh + (size_t)(q0 + row)*QVW + c*8, (char*)Qs + (it*4 + wave)*1024);
            gload16(Kh + (size_t)(k0 + row)*QVW + c*8, (char*)Ks + (it*4 + wave)*1024);
        }
    }
    if (tid < 64) padf[tid] = (amask[b*SS + q0 + tid] != 0) ? 1.f : 0.f;
    __syncthreads();

    ushort_t* Et = E + (size_t)(b*HH + h)*NPAIR*4096 + (size_t)(qt*(qt+1)/2 + kt)*4096;

    #pragma unroll
    for (int ns = 0; ns < 4; ++ns) {
        f32x4 sa = (f32x4){0.f, 0.f, 0.f, 0.f};
        #pragma unroll
        for (int ks = 0; ks < 3; ++ks) {
            const short8 aq = *(short8*)&Qs[((wave*16 + n)*16 + ((ks*4 + quad) ^ sx))*8];
            const short8 bk = *(short8*)&Ks[((ns*16   + n)*16 + ((ks*4 + quad) ^ sx))*8];
            sa = __builtin_amdgcn_mfma_f32_16x16x32_bf16(aq, bk, sa, 0, 0, 0);
        }
        const int kl = ns*16 + n;
        const int keyg = k0 + kl;
        float s = 0.f;
        #pragma unroll
        for (int r = 0; r < 4; ++r) {
            const int qrow = wave*16 + quad*4 + r;
            const bool dead = (padf[qrow] != 0.f) || (keyg > q0 + qrow);
            const float e = dead ? 0.f : __expf(sa[r] * SM_SCALE);
            s += e;
            Et[qrow * 64 + kl] = f2b(e);
        }
        s += __shfl_xor(s, 16);
        s += __shfl_xor(s, 32);
        if (quad == 0) colsum[wave][kl] = s;
    }
    __syncthreads();
    if (tid < 64) {
        const float s = colsum[0][tid] + colsum[1][tid] + colsum[2][tid] + colsum[3][tid];
        lpart[((size_t)(b*HH + h)*NTILES + qt)*SS + k0 + tid] = s;
    }
}

// ---------------------------------------------------------------------------
// V' transpose+scale: QV's KV half -> (B,H,DK,S) bf16 scaled by 1/l_k, where
// l_k = sum over qt>=kt of lpart. Dead column -> 0. grid (S/64, H, B).
// ---------------------------------------------------------------------------
__global__ __launch_bounds__(256) void transpose_scale(
    const ushort_t* __restrict__ QV, const float* __restrict__ lpart,
    ushort_t* __restrict__ Vt)
{
    __shared__ ushort_t T[64][104];
    __shared__ float rlv[64];
    const int tid = threadIdx.x;
    const int k0 = blockIdx.x * 64, h = blockIdx.y, b = blockIdx.z;
    const ushort_t* src = QV + (size_t)b*SS*QVW + DD + h*DKK;
    for (int s = tid; s < 768; s += 256) {
        const int r = s / 12, c = s % 12;
        *(short8*)&T[r][c*8] = *(const short8*)(src + (size_t)(k0 + r)*QVW + c*8);
    }
    if (tid < 64) {
        const float* lp = lpart + (size_t)(b*HH + h)*NTILES*SS;
        float l = 0.f;
        for (int qt = k0 >> 6; qt < NTILES; ++qt) l += lp[(size_t)qt*SS + k0 + tid];
        rlv[tid] = (l > 0.f) ? (1.f / l) : 0.f;
    }
    __syncthreads();
    ushort_t* dst = Vt + ((size_t)b*HH + h)*DKK*SS;
    for (int s = tid; s < 768; s += 256) {
        const int dk = s >> 3, c = s & 7;
        short8 v;
        #pragma unroll
        for (int i = 0; i < 8; ++i)
            v[i] = (short)f2b(b2f(T[c*8 + i][dk]) * rlv[c*8 + i]);
        *(short8*)(dst + (size_t)dk*SS + k0 + c*8) = v;
    }
}

// ---------------------------------------------------------------------------
// PV: O = E @ V'. LDS-staged MFMA GEMM with XOR swizzle; causal pair
// {px, 15-px} for uniform work; grid (8, H, B).
// ---------------------------------------------------------------------------
__global__ __launch_bounds__(256) void attn_pv(
    const ushort_t* __restrict__ E, const ushort_t* __restrict__ Vt,
    float* __restrict__ O)
{
    __shared__ ushort_t Es[64*64];    // 8 KB
    __shared__ ushort_t Vs[96*64];    // 12 KB
    const int tid = threadIdx.x, lane = tid & 63, wave = tid >> 6;
    const int n = lane & 15, quad = lane >> 4;
    const int sx = n & 7;
    const int px = blockIdx.x;
    const int h = blockIdx.y, b = blockIdx.z;
    const ushort_t* Eb  = E + (size_t)(b*HH + h)*NPAIR*4096;
    const ushort_t* Vth = Vt + ((size_t)b*HH + h)*DKK*SS;

    #pragma unroll
    for (int half = 0; half < 2; ++half) {
        const int qt = half ? (15 - px) : px;
        const int q0 = qt * 64;
        f32x4 acc[6];
        #pragma unroll
        for (int t = 0; t < 6; ++t) acc[t] = (f32x4){0.f, 0.f, 0.f, 0.f};
        const ushort_t* Eq = Eb + (size_t)(qt*(qt+1)/2)*4096;

        for (int kt = 0; kt <= qt; ++kt) {
            const ushort_t* Et = Eq + (size_t)kt*4096;
            #pragma unroll
            for (int it = 0; it < 2; ++it) {
                const int u = (it*4 + wave)*64 + lane;   // 0..511
                const int row = u >> 3, c = (u & 7) ^ (row & 7);
                gload16(Et + (size_t)row*64 + c*8, (char*)Es + (it*4 + wave)*1024);
            }
            #pragma unroll
            for (int it = 0; it < 3; ++it) {
                const int u = (it*4 + wave)*64 + lane;   // 0..767
                const int row = u >> 3, c = (u & 7) ^ (row & 7);
                gload16(Vth + (size_t)row*SS + kt*64 + c*8, (char*)Vs + (it*4 + wave)*1024);
            }
            __syncthreads();
            #pragma unroll
            for (int kk = 0; kk < 2; ++kk) {
                const short8 ae = *(short8*)&Es[((wave*16 + n)*8 + ((kk*4 + quad) ^ sx))*8];
                #pragma unroll
                for (int nt = 0; nt < 6; ++nt) {
                    const short8 bv = *(short8*)&Vs[((nt*16 + n)*8 + ((kk*4 + quad) ^ sx))*8];
                    acc[nt] = __builtin_amdgcn_mfma_f32_16x16x32_bf16(ae, bv, acc[nt], 0, 0, 0);
                }
            }
            __syncthreads();
        }
        #pragma unroll
        for (int nt = 0; nt < 6; ++nt) {
            #pragma unroll
            for (int r = 0; r < 4; ++r) {
                const int q = q0 + wave*16 + quad*4 + r;
                O[((size_t)b*SS + q)*DD + h*DKK + nt*16 + n] = acc[nt][r];
            }
        }
    }
}

// ---------------------------------------------------------------------------
// Residual + LayerNorm (+ optional bf16 copy). One block per row.
// ---------------------------------------------------------------------------
__device__ __forceinline__ float block_sum256(float s, float* tmp4)
{
    #pragma unroll
    for (int off = 32; off > 0; off >>= 1) s += __shfl_down(s, off);
    __syncthreads();
    if ((threadIdx.x & 63) == 0) tmp4[threadIdx.x >> 6] = s;
    __syncthreads();
    return tmp4[0] + tmp4[1] + tmp4[2] + tmp4[3];
}

__global__ __launch_bounds__(256) void resid_ln(
    const float* __restrict__ X, const float* __restrict__ R,
    const float* __restrict__ g, const float* __restrict__ beta,
    float* __restrict__ Out, ushort_t* __restrict__ OutB)
{
    __shared__ float tmp4[4];
    const int row = blockIdx.x;
    const int tid = threadIdx.x;
    const float* xp = X + (size_t)row * DD;
    const float* rp = R + (size_t)row * DD;
    float v[3], s = 0.f;
    #pragma unroll
    for (int i = 0; i < 3; ++i) {
        v[i] = xp[tid + 256*i] + rp[tid + 256*i];
        s += v[i];
    }
    const float mu = block_sum256(s, tmp4) * (1.f / DD);
    float qv = 0.f;
    #pragma unroll
    for (int i = 0; i < 3; ++i) { const float d = v[i] - mu; qv += d * d; }
    const float inv = rsqrtf(block_sum256(qv, tmp4) * (1.f / DD) + 1e-5f);
    #pragma unroll
    for (int i = 0; i < 3; ++i) {
        const int c = tid + 256*i;
        const float o = (v[i] - mu) * inv * g[c] + beta[c];
        Out[(size_t)row * DD + c] = o;
        if (OutB) OutB[(size_t)row * DD + c] = f2b(o);
    }
}

// ---------------------------------------------------------------------------
extern "C" void kernel_launch(void* const* d_in, const int* in_sizes, int n_in,
                              void* d_out, int out_size, void* d_ws, size_t ws_size,
                              hipStream_t stream)
{
    (void)in_sizes; (void)n_in; (void)out_size; (void)ws_size;
    const float* x0    = (const float*)d_in[0];
    const int*   amask = (const int*)d_in[1];
    const float* a1_Wq = (const float*)d_in[2];
    const float* a1_bq = (const float*)d_in[3];
    const float* a1_Wv = (const float*)d_in[4];
    const float* a1_bv = (const float*)d_in[5];
    const float* a1_g  = (const float*)d_in[6];
    const float* a1_b  = (const float*)d_in[7];
    const float* a2_Wq = (const float*)d_in[8];
    const float* a2_bq = (const float*)d_in[9];
    const float* a2_Wv = (const float*)d_in[10];
    const float* a2_bv = (const float*)d_in[11];
    const float* a2_g  = (const float*)d_in[12];
    const float* a2_b  = (const float*)d_in[13];
    const float* f_W1  = (const float*)d_in[14];
    const float* f_b1  = (const float*)d_in[15];
    const float* f_W2  = (const float*)d_in[16];
    const float* f_b2  = (const float*)d_in[17];
    const float* f_g   = (const float*)d_in[18];
    const float* f_b   = (const float*)d_in[19];

    char* ws = (char*)d_ws;
    size_t off = 0;
    auto alloc = [&](size_t bytes) { void* p = ws + off; off += (bytes + 255) & ~(size_t)255; return p; };
    ushort_t* WqvT1 = (ushort_t*)alloc((size_t)QVW*DD*2);   // rows 0..767 Wq^T, 768..1535 Wv^T
    ushort_t* WqvT2 = (ushort_t*)alloc((size_t)QVW*DD*2);
    ushort_t* W1T   = (ushort_t*)alloc((size_t)DD*FFF*2);
    ushort_t* W2T   = (ushort_t*)alloc((size_t)DD*FFF*2);
    ushort_t* xb    = (ushort_t*)alloc((size_t)MM*DD*2);
    ushort_t* QVb   = (ushort_t*)alloc((size_t)MM*QVW*2);   // Q | KV merged; aliased as hb
    ushort_t* hb    = QVb;                                  // M x FF bf16
    ushort_t* Vtb   = (ushort_t*)alloc((size_t)MM*DD*2);    // (B,H,DK,S)
    float* t0    = (float*)alloc((size_t)MM*DD*4);
    float* lpart = (float*)alloc((size_t)BB*HH*NTILES*SS*4);  // 4 MB partial column sums
    ushort_t* Ebuf = (ushort_t*)alloc((size_t)BB*HH*NPAIR*4096*2);   // 71.3 MB
    float* out = (float*)d_out;

    const dim3 blk(256);
    const dim3 gsc(NPAIR, HH, BB);
    const dim3 gpv(NTILES/2, HH, BB);
    const dim3 gtr(SS/64, HH, BB);
    const dim3 gqv(QVW/128, MM/128);
    const dim3 gf1(FFF/128, MM/128);
    const dim3 gf2(DD/128, MM/128);

    castWT4<<<dim3(DD/32, DD/32, 4), blk, 0, stream>>>(
        a1_Wq, a1_Wv, a2_Wq, a2_Wv,
        WqvT1, WqvT1 + (size_t)DD*DD, WqvT2, WqvT2 + (size_t)DD*DD);
    castWT<<<dim3(FFF/32, DD/32), blk, 0, stream>>>(f_W1, W1T, DD, FFF);
    castWT<<<dim3(DD/32, FFF/32), blk, 0, stream>>>(f_W2, W2T, FFF, DD);
    cast_f2b<<<(MM*DD/4 + 255)/256, blk, 0, stream>>>(x0, xb, MM*DD/4);

    // ---- layer 1 ----
    gemm_bt<1,0><<<gqv, blk, 0, stream>>>(xb, WqvT1, a1_bq, a1_bv, DD, QVb, DD, QVW);
    attn_scores<<<gsc, blk, 0, stream>>>(QVb, amask, Ebuf, lpart);
    transpose_scale<<<gtr, blk, 0, stream>>>(QVb, lpart, Vtb);
    attn_pv<<<gpv, blk, 0, stream>>>(Ebuf, Vtb, t0);
    resid_ln<<<dim3(MM), blk, 0, stream>>>(t0, x0, a1_g, a1_b, t0, xb);      // x1

    // ---- layer 2 ----
    gemm_bt<1,0><<<gqv, blk, 0, stream>>>(xb, WqvT2, a2_bq, a2_bv, DD, QVb, DD, QVW);
    attn_scores<<<gsc, blk, 0, stream>>>(QVb, amask, Ebuf, lpart);
    transpose_scale<<<gtr, blk, 0, stream>>>(QVb, lpart, Vtb);
    attn_pv<<<gpv, blk, 0, stream>>>(Ebuf, Vtb, out);
    resid_ln<<<dim3(MM), blk, 0, stream>>>(out, t0, a2_g, a2_b, out, xb);    // x2

    // ---- FFN ----
    gemm_bt<1,1><<<gf1, blk, 0, stream>>>(xb, W1T, f_b1, f_b1, FFF, hb, DD, FFF);
    gemm_bt<0,0><<<gf2, blk, 0, stream>>>(hb, W2T, f_b2, f_b2, DD, t0, FFF, DD);
    resid_ln<<<dim3(MM), blk, 0, stream>>>(t0, out, f_g, f_b, out, (ushort_t*)nullptr);
}

// Round 7
// 407.148 us; speedup vs baseline: 1.2899x; 1.0849x over previous
//
#include <hip/hip_runtime.h>
#include <cstddef>

#define BB 8
#define SS 1024
#define DD 768
#define HH 8
#define DKK 96
#define FFF 1024
#define MM (BB*SS)
#define QVW 1536                       // merged Q|KV row width
#define SM_SCALE 0.10206207261596577f  // 1/sqrt(96)
#define NTILES 16
#define NPAIR  136                     // 16*17/2 packed causal tiles

typedef unsigned short ushort_t;
typedef short short8 __attribute__((ext_vector_type(8)));
typedef float f32x4 __attribute__((ext_vector_type(4)));
typedef ushort_t us4 __attribute__((ext_vector_type(4)));

__device__ __forceinline__ ushort_t f2b(float f) {
    union { float f; unsigned u; } x; x.f = f;
    unsigned r = x.u + 0x7fffu + ((x.u >> 16) & 1u);   // RNE
    return (ushort_t)(r >> 16);
}
__device__ __forceinline__ float b2f(ushort_t u) {
    union { unsigned u; float f; } x; x.u = ((unsigned)u) << 16;
    return x.f;
}
// async global->LDS, 16B per lane; LDS dest = wave-uniform base + lane*16
__device__ __forceinline__ void gload16(const ushort_t* g, void* lds_base) {
    __builtin_amdgcn_global_load_lds(
        (const __attribute__((address_space(1))) unsigned int*)g,
        (__attribute__((address_space(3))) unsigned int*)lds_base, 16, 0, 0);
}

// ---------------------------------------------------------------------------
// Weight cast+transpose: W (KxN fp32) -> Wt (NxK bf16). grid (N/32, K/32).
// ---------------------------------------------------------------------------
__global__ __launch_bounds__(256) void castWT(
    const float* __restrict__ W, ushort_t* __restrict__ Wt, int K, int N)
{
    __shared__ float T[32][33];
    const int tx = threadIdx.x & 31, ty = threadIdx.x >> 5;
    const int n0 = blockIdx.x * 32, k0 = blockIdx.y * 32;
    #pragma unroll
    for (int r = 0; r < 4; ++r)
        T[ty + 8*r][tx] = W[(size_t)(k0 + ty + 8*r) * N + n0 + tx];
    __syncthreads();
    #pragma unroll
    for (int r = 0; r < 4; ++r)
        Wt[(size_t)(n0 + ty + 8*r) * K + k0 + tx] = f2b(T[tx][ty + 8*r]);
}

// 4x DDxDD weights in one launch. grid (DD/32, DD/32, 4).
__global__ __launch_bounds__(256) void castWT4(
    const float* __restrict__ Wa, const float* __restrict__ Wb,
    const float* __restrict__ Wc, const float* __restrict__ Wd,
    ushort_t* __restrict__ Ta, ushort_t* __restrict__ Tb,
    ushort_t* __restrict__ Tc, ushort_t* __restrict__ Td)
{
    __shared__ float T[32][33];
    const float* W; ushort_t* Wt;
    switch (blockIdx.z) {
        case 0:  W = Wa; Wt = Ta; break;
        case 1:  W = Wb; Wt = Tb; break;
        case 2:  W = Wc; Wt = Tc; break;
        default: W = Wd; Wt = Td; break;
    }
    const int tx = threadIdx.x & 31, ty = threadIdx.x >> 5;
    const int n0 = blockIdx.x * 32, k0 = blockIdx.y * 32;
    #pragma unroll
    for (int r = 0; r < 4; ++r)
        T[ty + 8*r][tx] = W[(size_t)(k0 + ty + 8*r) * DD + n0 + tx];
    __syncthreads();
    #pragma unroll
    for (int r = 0; r < 4; ++r)
        Wt[(size_t)(n0 + ty + 8*r) * DD + k0 + tx] = f2b(T[tx][ty + 8*r]);
}

__global__ __launch_bounds__(256) void cast_f2b(
    const float* __restrict__ in, ushort_t* __restrict__ out, int n4)
{
    const int i = blockIdx.x * 256 + threadIdx.x;
    if (i >= n4) return;
    const float4 v = ((const float4*)in)[i];
    us4 o; o.x = f2b(v.x); o.y = f2b(v.y); o.z = f2b(v.z); o.w = f2b(v.w);
    ((us4*)out)[i] = o;
}

// ---------------------------------------------------------------------------
// MFMA GEMM: C(bf16) = A(MxK) @ Bt(NxK)^T + bias. 128x128, BK=64, 4 waves.
// global_load_lds staging with XOR bank swizzle. Epilogue repacks acc into
// a padded LDS C-tile (136-ushort rows) then stores b128 coalesced.
// ---------------------------------------------------------------------------
template<int RELU>
__global__ __launch_bounds__(256) void gemm_bt(
    const ushort_t* __restrict__ A, const ushort_t* __restrict__ Bt,
    const float* __restrict__ bias, const float* __restrict__ bias2, int bN,
    ushort_t* __restrict__ C, int K, int N)
{
    __shared__ ushort_t S[128*136];            // >= As(8192)+Bs(8192); C-tile 128x136
    ushort_t* As = S;
    ushort_t* Bs = S + 128*64;
    const int tid  = threadIdx.x;
    const int lane = tid & 63, wave = tid >> 6;
    const int wm = wave >> 1, wn = wave & 1;
    const int n = lane & 15, quad = lane >> 4;
    const int sx = n & 7;              // read-side swizzle key
    const int bm = blockIdx.y * 128, bn = blockIdx.x * 128;

    f32x4 acc[4][4];
    #pragma unroll
    for (int i = 0; i < 4; ++i)
        #pragma unroll
        for (int j = 0; j < 4; ++j) acc[i][j] = (f32x4){0.f, 0.f, 0.f, 0.f};

    for (int k0 = 0; k0 < K; k0 += 64) {
        #pragma unroll
        for (int it = 0; it < 4; ++it) {
            const int u   = (it*4 + wave)*64 + lane;   // LDS 16B unit, 0..1023
            const int row = u >> 3;
            const int c   = (u & 7) ^ (row & 7);       // swizzled global chunk
            gload16(A  + (size_t)(bm + row) * K + k0 + c*8, (char*)As + (it*4 + wave)*1024);
            gload16(Bt + (size_t)(bn + row) * K + k0 + c*8, (char*)Bs + (it*4 + wave)*1024);
        }
        __syncthreads();
        #pragma unroll
        for (int ks = 0; ks < 2; ++ks) {
            short8 af[4], bf[4];
            #pragma unroll
            for (int i = 0; i < 4; ++i)
                af[i] = *(short8*)&As[((wm*64 + i*16 + n)*8 + ((ks*4 + quad) ^ sx))*8];
            #pragma unroll
            for (int j = 0; j < 4; ++j)
                bf[j] = *(short8*)&Bs[((wn*64 + j*16 + n)*8 + ((ks*4 + quad) ^ sx))*8];
            #pragma unroll
            for (int i = 0; i < 4; ++i)
                #pragma unroll
                for (int j = 0; j < 4; ++j)
                    acc[i][j] = __builtin_amdgcn_mfma_f32_16x16x32_bf16(af[i], bf[j], acc[i][j], 0, 0, 0);
        }
        __syncthreads();
    }
    // epilogue: acc -> LDS C-tile (bf16, padded rows) -> b128 stores
    #pragma unroll
    for (int j = 0; j < 4; ++j) {
        const int col = wn*64 + j*16 + n;
        const int gcol = bn + col;
        const float bsv = (gcol < bN) ? bias[gcol] : bias2[gcol - bN];
        #pragma unroll
        for (int i = 0; i < 4; ++i) {
            const int lrow = wm*64 + i*16 + quad*4;
            #pragma unroll
            for (int r = 0; r < 4; ++r) {
                float v = acc[i][j][r] + bsv;
                if (RELU) v = fmaxf(v, 0.f);
                S[(lrow + r)*136 + col] = f2b(v);
            }
        }
    }
    __syncthreads();
    #pragma unroll
    for (int it = 0; it < 8; ++it) {
        const int u = it*256 + tid;              // 0..2047 b128 units
        const int grow = u >> 4, gc = u & 15;
        *(short8*)(C + (size_t)(bm + grow)*N + bn + gc*8) = *(short8*)&S[grow*136 + gc*8];
    }
}

// ---------------------------------------------------------------------------
// Attention scores: one block per packed causal tile (grid NPAIR, H, B).
// E = exp(scale*QK^T) (masked -> 0); E tile staged in padded LDS then
// written b128; per-(qt,column) sums to lpart[b,h,qt,k] (no atomics).
// ---------------------------------------------------------------------------
__global__ __launch_bounds__(256) void attn_scores(
    const ushort_t* __restrict__ QV, const int* __restrict__ amask,
    ushort_t* __restrict__ E, float* __restrict__ lpart)
{
    __shared__ ushort_t Qs[64*128];
    __shared__ ushort_t Ks[64*128];
    __shared__ ushort_t Etile[64*72];
    __shared__ float colsum[4][64];
    __shared__ float padf[64];
    const int tid = threadIdx.x, lane = tid & 63, wave = tid >> 6;
    const int n = lane & 15, quad = lane >> 4;
    const int sx = n & 7;
    const int t = blockIdx.x;
    int qt = (int)((-1.f + sqrtf(1.f + 8.f*(float)t)) * 0.5f);
    if ((qt+1)*(qt+2)/2 <= t) ++qt;
    if (qt*(qt+1)/2 > t) --qt;
    const int kt = t - qt*(qt+1)/2;
    const int q0 = qt*64, k0 = kt*64;
    const int h = blockIdx.y, b = blockIdx.z;
    const ushort_t* Qh = QV + (size_t)b*SS*QVW + h*DKK;
    const ushort_t* Kh = QV + (size_t)b*SS*QVW + DD + h*DKK;

    #pragma unroll
    for (int it = 0; it < 4; ++it) {
        const int u = (it*4 + wave)*64 + lane;     // LDS unit, 0..1023
        const int row = u >> 4;
        const int c = (u & 15) ^ (row & 7);        // 0..15; valid if <12
        if (c < 12) {
            gload16(Qh + (size_t)(q0 + row)*QVW + c*8, (char*)Qs + (it*4 + wave)*1024);
            gload16(Kh + (size_t)(k0 + row)*QVW + c*8, (char*)Ks + (it*4 + wave)*1024);
        }
    }
    if (tid < 64) padf[tid] = (amask[b*SS + q0 + tid] != 0) ? 1.f : 0.f;
    __syncthreads();

    ushort_t* Et = E + (size_t)(b*HH + h)*NPAIR*4096 + (size_t)(qt*(qt+1)/2 + kt)*4096;

    #pragma unroll
    for (int ns = 0; ns < 4; ++ns) {
        f32x4 sa = (f32x4){0.f, 0.f, 0.f, 0.f};
        #pragma unroll
        for (int ks = 0; ks < 3; ++ks) {
            const short8 aq = *(short8*)&Qs[((wave*16 + n)*16 + ((ks*4 + quad) ^ sx))*8];
            const short8 bk = *(short8*)&Ks[((ns*16   + n)*16 + ((ks*4 + quad) ^ sx))*8];
            sa = __builtin_amdgcn_mfma_f32_16x16x32_bf16(aq, bk, sa, 0, 0, 0);
        }
        const int kl = ns*16 + n;
        const int keyg = k0 + kl;
        float s = 0.f;
        #pragma unroll
        for (int r = 0; r < 4; ++r) {
            const int qrow = wave*16 + quad*4 + r;
            const bool dead = (padf[qrow] != 0.f) || (keyg > q0 + qrow);
            const float e = dead ? 0.f : __expf(sa[r] * SM_SCALE);
            s += e;
            Etile[qrow*72 + kl] = f2b(e);
        }
        s += __shfl_xor(s, 16);
        s += __shfl_xor(s, 32);
        if (quad == 0) colsum[wave][kl] = s;
    }
    __syncthreads();
    #pragma unroll
    for (int it = 0; it < 2; ++it) {
        const int u = it*256 + tid;                // 0..511 b128 units
        const int grow = u >> 3, gc = u & 7;
        *(short8*)(Et + grow*64 + gc*8) = *(short8*)&Etile[grow*72 + gc*8];
    }
    if (tid < 64) {
        const float s = colsum[0][tid] + colsum[1][tid] + colsum[2][tid] + colsum[3][tid];
        lpart[((size_t)(b*HH + h)*NTILES + qt)*SS + k0 + tid] = s;
    }
}

// ---------------------------------------------------------------------------
// V' transpose+scale: QV's KV half -> (B,H,DK,S) bf16 scaled by 1/l_k, where
// l_k = sum over qt>=kt of lpart. Dead column -> 0. grid (S/64, H, B).
// ---------------------------------------------------------------------------
__global__ __launch_bounds__(256) void transpose_scale(
    const ushort_t* __restrict__ QV, const float* __restrict__ lpart,
    ushort_t* __restrict__ Vt)
{
    __shared__ ushort_t T[64][104];
    __shared__ float rlv[64];
    const int tid = threadIdx.x;
    const int k0 = blockIdx.x * 64, h = blockIdx.y, b = blockIdx.z;
    const ushort_t* src = QV + (size_t)b*SS*QVW + DD + h*DKK;
    for (int s = tid; s < 768; s += 256) {
        const int r = s / 12, c = s % 12;
        *(short8*)&T[r][c*8] = *(const short8*)(src + (size_t)(k0 + r)*QVW + c*8);
    }
    if (tid < 64) {
        const float* lp = lpart + (size_t)(b*HH + h)*NTILES*SS;
        float l = 0.f;
        for (int qt = k0 >> 6; qt < NTILES; ++qt) l += lp[(size_t)qt*SS + k0 + tid];
        rlv[tid] = (l > 0.f) ? (1.f / l) : 0.f;
    }
    __syncthreads();
    ushort_t* dst = Vt + ((size_t)b*HH + h)*DKK*SS;
    for (int s = tid; s < 768; s += 256) {
        const int dk = s >> 3, c = s & 7;
        short8 v;
        #pragma unroll
        for (int i = 0; i < 8; ++i)
            v[i] = (short)f2b(b2f(T[c*8 + i][dk]) * rlv[c*8 + i]);
        *(short8*)(dst + (size_t)dk*SS + k0 + c*8) = v;
    }
}

// ---------------------------------------------------------------------------
// PV: O(bf16) = E @ V'. LDS-staged MFMA GEMM with XOR swizzle; causal pair
// {px, 15-px} for uniform work; grid (8, H, B).
// ---------------------------------------------------------------------------
__global__ __launch_bounds__(256) void attn_pv(
    const ushort_t* __restrict__ E, const ushort_t* __restrict__ Vt,
    ushort_t* __restrict__ O)
{
    __shared__ ushort_t Es[64*64];    // 8 KB
    __shared__ ushort_t Vs[96*64];    // 12 KB
    const int tid = threadIdx.x, lane = tid & 63, wave = tid >> 6;
    const int n = lane & 15, quad = lane >> 4;
    const int sx = n & 7;
    const int px = blockIdx.x;
    const int h = blockIdx.y, b = blockIdx.z;
    const ushort_t* Eb  = E + (size_t)(b*HH + h)*NPAIR*4096;
    const ushort_t* Vth = Vt + ((size_t)b*HH + h)*DKK*SS;

    #pragma unroll
    for (int half = 0; half < 2; ++half) {
        const int qt = half ? (15 - px) : px;
        const int q0 = qt * 64;
        f32x4 acc[6];
        #pragma unroll
        for (int t = 0; t < 6; ++t) acc[t] = (f32x4){0.f, 0.f, 0.f, 0.f};
        const ushort_t* Eq = Eb + (size_t)(qt*(qt+1)/2)*4096;

        for (int kt = 0; kt <= qt; ++kt) {
            const ushort_t* Et = Eq + (size_t)kt*4096;
            #pragma unroll
            for (int it = 0; it < 2; ++it) {
                const int u = (it*4 + wave)*64 + lane;   // 0..511
                const int row = u >> 3, c = (u & 7) ^ (row & 7);
                gload16(Et + (size_t)row*64 + c*8, (char*)Es + (it*4 + wave)*1024);
            }
            #pragma unroll
            for (int it = 0; it < 3; ++it) {
                const int u = (it*4 + wave)*64 + lane;   // 0..767
                const int row = u >> 3, c = (u & 7) ^ (row & 7);
                gload16(Vth + (size_t)row*SS + kt*64 + c*8, (char*)Vs + (it*4 + wave)*1024);
            }
            __syncthreads();
            #pragma unroll
            for (int kk = 0; kk < 2; ++kk) {
                const short8 ae = *(short8*)&Es[((wave*16 + n)*8 + ((kk*4 + quad) ^ sx))*8];
                #pragma unroll
                for (int nt = 0; nt < 6; ++nt) {
                    const short8 bv = *(short8*)&Vs[((nt*16 + n)*8 + ((kk*4 + quad) ^ sx))*8];
                    acc[nt] = __builtin_amdgcn_mfma_f32_16x16x32_bf16(ae, bv, acc[nt], 0, 0, 0);
                }
            }
            __syncthreads();
        }
        #pragma unroll
        for (int nt = 0; nt < 6; ++nt) {
            #pragma unroll
            for (int r = 0; r < 4; ++r) {
                const int q = q0 + wave*16 + quad*4 + r;
                O[((size_t)b*SS + q)*DD + h*DKK + nt*16 + n] = f2b(acc[nt][r]);
            }
        }
    }
}

// ---------------------------------------------------------------------------
// Residual + LayerNorm. X, R dtype per template; writes bf16 (or fp32 final).
// One block per row.
// ---------------------------------------------------------------------------
__device__ __forceinline__ float block_sum256(float s, float* tmp4)
{
    #pragma unroll
    for (int off = 32; off > 0; off >>= 1) s += __shfl_down(s, off);
    __syncthreads();
    if ((threadIdx.x & 63) == 0) tmp4[threadIdx.x >> 6] = s;
    __syncthreads();
    return tmp4[0] + tmp4[1] + tmp4[2] + tmp4[3];
}

template<int XBF, int RBF, int OUTF32>
__global__ __launch_bounds__(256) void resid_ln(
    const void* __restrict__ X, const void* __restrict__ R,
    const float* __restrict__ g, const float* __restrict__ beta,
    ushort_t* __restrict__ OutB, float* __restrict__ OutF)
{
    __shared__ float tmp4[4];
    const int row = blockIdx.x;
    const int tid = threadIdx.x;
    float v[3], s = 0.f;
    #pragma unroll
    for (int i = 0; i < 3; ++i) {
        const size_t idx = (size_t)row * DD + tid + 256*i;
        const float xv = XBF ? b2f(((const ushort_t*)X)[idx]) : ((const float*)X)[idx];
        const float rv = RBF ? b2f(((const ushort_t*)R)[idx]) : ((const float*)R)[idx];
        v[i] = xv + rv;
        s += v[i];
    }
    const float mu = block_sum256(s, tmp4) * (1.f / DD);
    float qv = 0.f;
    #pragma unroll
    for (int i = 0; i < 3; ++i) { const float d = v[i] - mu; qv += d * d; }
    const float inv = rsqrtf(block_sum256(qv, tmp4) * (1.f / DD) + 1e-5f);
    #pragma unroll
    for (int i = 0; i < 3; ++i) {
        const int c = tid + 256*i;
        const float o = (v[i] - mu) * inv * g[c] + beta[c];
        if (OUTF32) OutF[(size_t)row * DD + c] = o;
        else        OutB[(size_t)row * DD + c] = f2b(o);
    }
}

// ---------------------------------------------------------------------------
extern "C" void kernel_launch(void* const* d_in, const int* in_sizes, int n_in,
                              void* d_out, int out_size, void* d_ws, size_t ws_size,
                              hipStream_t stream)
{
    (void)in_sizes; (void)n_in; (void)out_size; (void)ws_size;
    const float* x0    = (const float*)d_in[0];
    const int*   amask = (const int*)d_in[1];
    const float* a1_Wq = (const float*)d_in[2];
    const float* a1_bq = (const float*)d_in[3];
    const float* a1_Wv = (const float*)d_in[4];
    const float* a1_bv = (const float*)d_in[5];
    const float* a1_g  = (const float*)d_in[6];
    const float* a1_b  = (const float*)d_in[7];
    const float* a2_Wq = (const float*)d_in[8];
    const float* a2_bq = (const float*)d_in[9];
    const float* a2_Wv = (const float*)d_in[10];
    const float* a2_bv = (const float*)d_in[11];
    const float* a2_g  = (const float*)d_in[12];
    const float* a2_b  = (const float*)d_in[13];
    const float* f_W1  = (const float*)d_in[14];
    const float* f_b1  = (const float*)d_in[15];
    const float* f_W2  = (const float*)d_in[16];
    const float* f_b2  = (const float*)d_in[17];
    const float* f_g   = (const float*)d_in[18];
    const float* f_b   = (const float*)d_in[19];

    char* ws = (char*)d_ws;
    size_t off = 0;
    auto alloc = [&](size_t bytes) { void* p = ws + off; off += (bytes + 255) & ~(size_t)255; return p; };
    ushort_t* WqvT1 = (ushort_t*)alloc((size_t)QVW*DD*2);   // rows 0..767 Wq^T, 768..1535 Wv^T
    ushort_t* WqvT2 = (ushort_t*)alloc((size_t)QVW*DD*2);
    ushort_t* W1T   = (ushort_t*)alloc((size_t)DD*FFF*2);
    ushort_t* W2T   = (ushort_t*)alloc((size_t)DD*FFF*2);
    ushort_t* xb0   = (ushort_t*)alloc((size_t)MM*DD*2);    // bf16(x0)
    ushort_t* xb1   = (ushort_t*)alloc((size_t)MM*DD*2);    // x1 (post-LN layer 1)
    ushort_t* xb2   = (ushort_t*)alloc((size_t)MM*DD*2);    // x2 (post-LN layer 2)
    ushort_t* Ob    = (ushort_t*)alloc((size_t)MM*DD*2);    // attention O / FFN y
    ushort_t* QVb   = (ushort_t*)alloc((size_t)MM*QVW*2);   // Q | KV merged; aliased as hb
    ushort_t* hb    = QVb;                                  // M x FF bf16
    ushort_t* Vtb   = (ushort_t*)alloc((size_t)MM*DD*2);    // (B,H,DK,S)
    float* lpart = (float*)alloc((size_t)BB*HH*NTILES*SS*4);  // 4 MB partial column sums
    ushort_t* Ebuf = (ushort_t*)alloc((size_t)BB*HH*NPAIR*4096*2);   // 71.3 MB
    float* out = (float*)d_out;

    const dim3 blk(256);
    const dim3 gsc(NPAIR, HH, BB);
    const dim3 gpv(NTILES/2, HH, BB);
    const dim3 gtr(SS/64, HH, BB);
    const dim3 gqv(QVW/128, MM/128);
    const dim3 gf1(FFF/128, MM/128);
    const dim3 gf2(DD/128, MM/128);

    castWT4<<<dim3(DD/32, DD/32, 4), blk, 0, stream>>>(
        a1_Wq, a1_Wv, a2_Wq, a2_Wv,
        WqvT1, WqvT1 + (size_t)DD*DD, WqvT2, WqvT2 + (size_t)DD*DD);
    castWT<<<dim3(FFF/32, DD/32), blk, 0, stream>>>(f_W1, W1T, DD, FFF);
    castWT<<<dim3(DD/32, FFF/32), blk, 0, stream>>>(f_W2, W2T, FFF, DD);
    cast_f2b<<<(MM*DD/4 + 255)/256, blk, 0, stream>>>(x0, xb0, MM*DD/4);

    // ---- layer 1 ----
    gemm_bt<0><<<gqv, blk, 0, stream>>>(xb0, WqvT1, a1_bq, a1_bv, DD, QVb, DD, QVW);
    attn_scores<<<gsc, blk, 0, stream>>>(QVb, amask, Ebuf, lpart);
    transpose_scale<<<gtr, blk, 0, stream>>>(QVb, lpart, Vtb);
    attn_pv<<<gpv, blk, 0, stream>>>(Ebuf, Vtb, Ob);
    resid_ln<1,0,0><<<dim3(MM), blk, 0, stream>>>(Ob, x0, a1_g, a1_b, xb1, nullptr);

    // ---- layer 2 ----
    gemm_bt<0><<<gqv, blk, 0, stream>>>(xb1, WqvT2, a2_bq, a2_bv, DD, QVb, DD, QVW);
    attn_scores<<<gsc, blk, 0, stream>>>(QVb, amask, Ebuf, lpart);
    transpose_scale<<<gtr, blk, 0, stream>>>(QVb, lpart, Vtb);
    attn_pv<<<gpv, blk, 0, stream>>>(Ebuf, Vtb, Ob);
    resid_ln<1,1,0><<<dim3(MM), blk, 0, stream>>>(Ob, xb1, a2_g, a2_b, xb2, nullptr);

    // ---- FFN ----
    gemm_bt<1><<<gf1, blk, 0, stream>>>(xb2, W1T, f_b1, f_b1, FFF, hb, DD, FFF);
    gemm_bt<0><<<gf2, blk, 0, stream>>>(hb, W2T, f_b2, f_b2, DD, Ob, FFF, DD);
    resid_ln<1,1,1><<<dim3(MM), blk, 0, stream>>>(Ob, xb2, f_g, f_b, nullptr, out);
}